// Round 6
// baseline (277.121 us; speedup 1.0000x reference)
//
#include <hip/hip_runtime.h>

#define B_TOT 16384
#define NQ 7
#define H 64
#define MD 28

// ws layout (floats), all dim-major [dim][B_TOT] for coalesced lane access
#define OFF_S0 0
#define OFF_S1 (64*B_TOT)
#define OFF_SV (128*B_TOT)
#define OFF_MI (156*B_TOT)
#define OFF_RP (184*B_TOT)
// total 191*B_TOT floats = 12.5 MiB

#define OIDX(hi,lo) ((hi)*((hi)-1)/2 + (lo))

__device__ __forceinline__ float fast_rcp(float x){ return __builtin_amdgcn_rcpf(x); }
__device__ __forceinline__ float sigmoid_f(float a) {
    return fast_rcp(1.0f + __expf(-a));
}
__device__ __forceinline__ float softplus_f(float a) {
    return fmaxf(a, 0.0f) + __logf(1.0f + __expf(-fabsf(a)));
}

// ============ K1: M-net fwd + JVP + 7x7 eigen + Loewner, lane-per-element ============
__global__ __launch_bounds__(64,1) void k1_fwd_eigen(
    const float* __restrict__ q, const float* __restrict__ dq, const float* __restrict__ tau,
    const float* __restrict__ WM0, const float* __restrict__ bM0,
    const float* __restrict__ WM1, const float* __restrict__ bM1,
    const float* __restrict__ WM2, const float* __restrict__ bM2,
    float* __restrict__ ws)
{
    __shared__ float W0s[H*NQ];    // row-major [o][d]
    __shared__ float W1s[H*H];     // row-major [o][k]
    __shared__ float W2Ts[H*MD];   // transposed [o][m] = WM2[m][o]
    __shared__ float b0s[H], b1s[H], b2s[MD];
    const int lane = threadIdx.x;
    for (int t=lane; t<H*NQ; t+=64) W0s[t]=WM0[t];
    for (int t=lane; t<H*H;  t+=64) W1s[t]=WM1[t];
    for (int t=lane; t<MD*H; t+=64) W2Ts[(t&63)*MD+(t>>6)]=WM2[t];
    b0s[lane]=bM0[lane]; b1s[lane]=bM1[lane];
    if (lane<MD) b2s[lane]=bM2[lane];
    __syncthreads();

    const int elem = blockIdx.x*64 + lane;

    float qv[NQ], dqv[NQ], tv[NQ];
    #pragma unroll
    for (int d=0; d<NQ; d++){ qv[d]=q[elem*NQ+d]; dqv[d]=dq[elem*NQ+d]; tv[d]=tau[elem*NQ+d]; }

    // ---- layer 0 (fully unrolled: z0/j0 must stay registers) ----
    float z0[H], j0[H];
    #pragma unroll
    for (int o=0;o<H;o++){
        float a=b0s[o], jd=0.0f;
        #pragma unroll
        for (int d=0;d<NQ;d++){ float w=W0s[o*NQ+d]; a=fmaf(w,qv[d],a); jd=fmaf(w,dqv[d],jd); }
        float s0v=sigmoid_f(a);
        z0[o]=softplus_f(a);
        j0[o]=s0v*jd;
        ws[OFF_S0 + o*B_TOT + elem]=s0v;   // coalesced
    }

    // ---- layer 1 + layer 2 fused (o-loop dynamic, k/m static) ----
    float x[MD], xd[MD];
    #pragma unroll
    for (int m=0;m<MD;m++){ x[m]=b2s[m]; xd[m]=0.0f; }
    #pragma unroll 1
    for (int o=0;o<H;o++){
        float a=b1s[o], jd=0.0f;
        #pragma unroll
        for (int k=0;k<H;k++){ float w=W1s[o*H+k]; a=fmaf(w,z0[k],a); jd=fmaf(w,j0[k],jd); }
        float s1v=sigmoid_f(a);
        ws[OFF_S1 + o*B_TOT + elem]=s1v;   // coalesced
        float z1=softplus_f(a), j1=s1v*jd;
        #pragma unroll
        for (int m=0;m<MD;m++){ float w=W2Ts[o*MD+m]; x[m]=fmaf(w,z1,x[m]); xd[m]=fmaf(w,j1,xd[m]); }
    }

    // ---- 7x7 Jacobi eigensolver (registers throughout) ----
    float Ad[NQ], Ao[21], V[49];
    #pragma unroll
    for (int i=0;i<NQ;i++) Ad[i] = x[i];
    #pragma unroll
    for (int t=0;t<21;t++) Ao[t] = x[NQ+t];
    #pragma unroll
    for (int t=0;t<49;t++) V[t] = 0.0f;
    #pragma unroll
    for (int i=0;i<NQ;i++) V[i*7+i] = 1.0f;

    #pragma unroll 1
    for (int sweep=0; sweep<6; sweep++){
        #pragma unroll
        for (int p=0;p<6;p++){
            #pragma unroll
            for (int qq=p+1;qq<7;qq++){
                float app=Ad[p], aqq=Ad[qq], apq=Ao[OIDX(qq,p)];
                bool rot = fabsf(apq) > 1e-20f;
                float apq_s = rot ? apq : 1.0f;
                float theta = (aqq-app) * fast_rcp(2.0f*apq_s);
                float t = fast_rcp(fabsf(theta)+sqrtf(fmaf(theta,theta,1.0f)));
                t = (theta<0.0f)? -t : t;
                t = rot ? t : 0.0f;
                float c = rsqrtf(fmaf(t,t,1.0f));
                float s = t*c;
                #pragma unroll
                for (int j=0;j<7;j++){
                    if (j==p || j==qq) continue;
                    float ajp = (j<p)?  Ao[OIDX(p,j)]  : Ao[OIDX(j,p)];
                    float ajq = (j<qq)? Ao[OIDX(qq,j)] : Ao[OIDX(j,qq)];
                    float np_ = fmaf(c,ajp,-s*ajq);
                    float nq_ = fmaf(s,ajp, c*ajq);
                    if (j<p)  Ao[OIDX(p,j)]  = np_; else Ao[OIDX(j,p)]  = np_;
                    if (j<qq) Ao[OIDX(qq,j)] = nq_; else Ao[OIDX(j,qq)] = nq_;
                }
                Ad[p]  = fmaf(-t,apq,app);
                Ad[qq] = fmaf( t,apq,aqq);
                Ao[OIDX(qq,p)] = 0.0f;
                #pragma unroll
                for (int j=0;j<7;j++){
                    float vp=V[j*7+p], vq=V[j*7+qq];
                    V[j*7+p]  = fmaf(c,vp,-s*vq);
                    V[j*7+qq] = fmaf(s,vp, c*vq);
                }
            }
        }
    }

    float ee[7], iee[7];
    #pragma unroll
    for (int i=0;i<7;i++){ ee[i] = __expf(Ad[i]); iee[i] = fast_rcp(ee[i]); }

    // Loewner off-diagonals
    float Ro[21];
    #pragma unroll
    for (int p=0;p<6;p++){
        #pragma unroll
        for (int qj=p+1;qj<7;qj++){
            float d = Ad[p]-Ad[qj];
            bool big = fabsf(d) > 1e-3f;
            float den = big ? d : 1.0f;
            float exact = (ee[p]-ee[qj])*fast_rcp(den);
            float ser = sqrtf(ee[p]*ee[qj]) * fmaf(d*d, (1.0f/24.0f), 1.0f);
            Ro[OIDX(qj,p)] = big ? exact : ser;
        }
    }

    // w = V^T dq
    float w[7];
    #pragma unroll
    for (int a=0;a<7;a++){
        float acc = 0.0f;
        #pragma unroll
        for (int j=0;j<7;j++) acc = fmaf(V[j*7+a], dqv[j], acc);
        w[a] = acc;
    }

    // Y = R o (w w^T); S = V Y V^T -> sv (cotangent, doubled off-diag)
    float Yd[7], Yo[21];
    #pragma unroll
    for (int a=0;a<7;a++) Yd[a] = ee[a]*w[a]*w[a];
    #pragma unroll
    for (int p=0;p<6;p++){
        #pragma unroll
        for (int qj=p+1;qj<7;qj++) Yo[OIDX(qj,p)] = Ro[OIDX(qj,p)]*w[p]*w[qj];
    }
    float P[49];
    #pragma unroll
    for (int i=0;i<7;i++){
        #pragma unroll
        for (int a=0;a<7;a++){
            float acc = 0.0f;
            #pragma unroll
            for (int c=0;c<7;c++){
                float y = (c==a)? Yd[a] : ((c<a)? Yo[OIDX(a,c)] : Yo[OIDX(c,a)]);
                acc = fmaf(V[i*7+c], y, acc);
            }
            P[i*7+a] = acc;
        }
    }
    #pragma unroll
    for (int i=0;i<7;i++){
        #pragma unroll
        for (int j=i;j<7;j++){
            float acc = 0.0f;
            #pragma unroll
            for (int a=0;a<7;a++) acc = fmaf(P[i*7+a], V[j*7+a], acc);
            if (i==j) ws[OFF_SV + i*B_TOT + elem] = acc;
            else      ws[OFF_SV + (NQ+OIDX(j,i))*B_TOT + elem] = 2.0f*acc;
        }
    }

    // Udot = sym(xd); T = V^T Udot V
    float P2[49];
    #pragma unroll
    for (int i=0;i<7;i++){
        #pragma unroll
        for (int a=0;a<7;a++){
            float acc = 0.0f;
            #pragma unroll
            for (int j=0;j<7;j++){
                float u = (i==j)? xd[i] : ((j<i)? xd[NQ+OIDX(i,j)] : xd[NQ+OIDX(j,i)]);
                acc = fmaf(u, V[j*7+a], acc);
            }
            P2[i*7+a] = acc;
        }
    }
    float Td[7], To[21];
    #pragma unroll
    for (int a=0;a<7;a++){
        float acc = 0.0f;
        #pragma unroll
        for (int i=0;i<7;i++) acc = fmaf(V[i*7+a], P2[i*7+a], acc);
        Td[a] = acc;
    }
    #pragma unroll
    for (int a=0;a<6;a++){
        #pragma unroll
        for (int bb=a+1;bb<7;bb++){
            float acc = 0.0f;
            #pragma unroll
            for (int i=0;i<7;i++) acc = fmaf(V[i*7+a], P2[i*7+bb], acc);
            To[OIDX(bb,a)] = acc;
        }
    }

    // zw = (R o T) w ; u1 = V zw   (Mdot*dq in original basis)
    float zw[7];
    #pragma unroll
    for (int a=0;a<7;a++){
        float acc = ee[a]*Td[a]*w[a];
        #pragma unroll
        for (int bb=0;bb<7;bb++){
            if (bb==a) continue;
            float z = (bb<a)? (Ro[OIDX(a,bb)]*To[OIDX(a,bb)]) : (Ro[OIDX(bb,a)]*To[OIDX(bb,a)]);
            acc = fmaf(z, w[bb], acc);
        }
        zw[a] = acc;
    }
    #pragma unroll
    for (int i=0;i<7;i++){
        float acc = 0.0f;
        #pragma unroll
        for (int a=0;a<7;a++) acc = fmaf(V[i*7+a], zw[a], acc);
        ws[OFF_RP + i*B_TOT + elem] = tv[i] - acc;
    }

    // Minv = V diag(1/ee) V^T
    #pragma unroll
    for (int i=0;i<7;i++){
        #pragma unroll
        for (int j=i;j<7;j++){
            float acc = 0.0f;
            #pragma unroll
            for (int a=0;a<7;a++) acc = fmaf(V[i*7+a]*iee[a], V[j*7+a], acc);
            if (i==j) ws[OFF_MI + i*B_TOT + elem] = acc;
            else      ws[OFF_MI + (NQ+OIDX(j,i))*B_TOT + elem] = acc;
        }
    }
}

// ============ K3: V-net fwd+rev (g), M-net rev (s), rhs, solve — lane-per-element ============
__global__ __launch_bounds__(64,1) void k3_rev(
    const float* __restrict__ q,
    const float* __restrict__ WM0, const float* __restrict__ WM1, const float* __restrict__ WM2,
    const float* __restrict__ WV0, const float* __restrict__ bV0,
    const float* __restrict__ WV1, const float* __restrict__ bV1,
    const float* __restrict__ WV2,
    const float* __restrict__ ws,
    float* __restrict__ out)
{
    __shared__ float WV0s[H*NQ];   // [o][d]
    __shared__ float WV1s[H*H];    // [o][k]
    __shared__ float W0s[H*NQ];    // [k][d]
    __shared__ float W1Ts[H*H];    // [k][i] = WM1[i][k]
    __shared__ float W2s[MD*H];    // [m][k]
    __shared__ float bv0s[H], bv1s[H], wv2s[H];
    const int lane = threadIdx.x;
    for (int t=lane; t<H*NQ; t+=64){ WV0s[t]=WV0[t]; W0s[t]=WM0[t]; }
    for (int t=lane; t<H*H;  t+=64){ WV1s[t]=WV1[t]; W1Ts[(t&63)*H+(t>>6)]=WM1[t]; }
    for (int t=lane; t<MD*H; t+=64) W2s[t]=WM2[t];
    bv0s[lane]=bV0[lane]; bv1s[lane]=bV1[lane]; wv2s[lane]=WV2[lane];
    __syncthreads();

    const int elem = blockIdx.x*64 + lane;

    float qv[NQ];
    #pragma unroll
    for (int d=0; d<NQ; d++) qv[d]=q[elem*NQ+d];

    // ---- V-net layer 0 ----
    float zv0[H], sv0[H];
    #pragma unroll
    for (int o=0;o<H;o++){
        float a=bv0s[o];
        #pragma unroll
        for (int d=0;d<NQ;d++) a=fmaf(WV0s[o*NQ+d],qv[d],a);
        zv0[o]=softplus_f(a);
        sv0[o]=sigmoid_f(a);
    }

    // ---- V-net layer 1 fwd + rev accumulate (same W row reused) ----
    float r0a[H];
    #pragma unroll
    for (int k=0;k<H;k++) r0a[k]=0.0f;
    #pragma unroll 1
    for (int o=0;o<H;o++){
        float a=bv1s[o];
        #pragma unroll
        for (int k=0;k<H;k++) a=fmaf(WV1s[o*H+k],zv0[k],a);
        float r1 = wv2s[o]*sigmoid_f(a);
        #pragma unroll
        for (int k=0;k<H;k++) r0a[k]=fmaf(WV1s[o*H+k],r1,r0a[k]);
    }

    // ---- g = WV0^T (sv0 .* r0a) ----
    float g[NQ];
    #pragma unroll
    for (int d=0;d<NQ;d++) g[d]=0.0f;
    #pragma unroll
    for (int k=0;k<H;k++){
        float r0f = sv0[k]*r0a[k];
        #pragma unroll
        for (int d=0;d<NQ;d++) g[d]=fmaf(WV0s[k*NQ+d],r0f,g[d]);
    }

    // ---- M-net reverse: acc1[k] = sum_m W2[m][k]*sv_m ----
    float acc1[H];
    #pragma unroll
    for (int k=0;k<H;k++) acc1[k]=0.0f;
    #pragma unroll 4
    for (int m=0;m<MD;m++){
        float svm = ws[OFF_SV + m*B_TOT + elem];
        #pragma unroll
        for (int k=0;k<H;k++) acc1[k]=fmaf(W2s[m*H+k],svm,acc1[k]);
    }
    // rr1f = s1 .* acc1
    float rr1f[H];
    #pragma unroll
    for (int k=0;k<H;k++) rr1f[k] = ws[OFF_S1 + k*B_TOT + elem]*acc1[k];

    // ---- s = W0^T (s0 .* (W1^T rr1f)) ----
    float sacc[NQ];
    #pragma unroll
    for (int d=0;d<NQ;d++) sacc[d]=0.0f;
    #pragma unroll 2
    for (int k=0;k<H;k++){
        float a2=0.0f;
        #pragma unroll
        for (int i=0;i<H;i++) a2=fmaf(W1Ts[k*H+i],rr1f[i],a2);
        float tk = ws[OFF_S0 + k*B_TOT + elem]*a2;
        #pragma unroll
        for (int d=0;d<NQ;d++) sacc[d]=fmaf(W0s[k*NQ+d],tk,sacc[d]);
    }

    // ---- rhs + solve ----
    float rhs[NQ];
    #pragma unroll
    for (int d=0;d<NQ;d++)
        rhs[d] = ws[OFF_RP + d*B_TOT + elem] + 0.5f*sacc[d] - g[d];

    float mi[MD];
    #pragma unroll
    for (int t=0;t<MD;t++) mi[t]=ws[OFF_MI + t*B_TOT + elem];

    #pragma unroll
    for (int i=0;i<NQ;i++){
        float acc=0.0f;
        #pragma unroll
        for (int j=0;j<NQ;j++){
            int idx = (j==i)? i : (NQ + ((j>i)? OIDX(j,i) : OIDX(i,j)));
            acc = fmaf(mi[idx], rhs[j], acc);
        }
        out[elem*NQ+i]=acc;
    }
}

extern "C" void kernel_launch(void* const* d_in, const int* in_sizes, int n_in,
                              void* d_out, int out_size, void* d_ws, size_t ws_size,
                              hipStream_t stream) {
    const float* q   = (const float*)d_in[0];
    const float* dq  = (const float*)d_in[1];
    const float* tau = (const float*)d_in[2];
    const float* WM0 = (const float*)d_in[3];
    const float* bM0 = (const float*)d_in[4];
    const float* WM1 = (const float*)d_in[5];
    const float* bM1 = (const float*)d_in[6];
    const float* WM2 = (const float*)d_in[7];
    const float* bM2 = (const float*)d_in[8];
    const float* WV0 = (const float*)d_in[9];
    const float* bV0 = (const float*)d_in[10];
    const float* WV1 = (const float*)d_in[11];
    const float* bV1 = (const float*)d_in[12];
    const float* WV2 = (const float*)d_in[13];
    float* ws  = (float*)d_ws;
    float* out = (float*)d_out;

    hipLaunchKernelGGL(k1_fwd_eigen, dim3(B_TOT/64), dim3(64), 0, stream,
                       q, dq, tau, WM0, bM0, WM1, bM1, WM2, bM2, ws);
    hipLaunchKernelGGL(k3_rev, dim3(B_TOT/64), dim3(64), 0, stream,
                       q, WM0, WM1, WM2, WV0, bV0, WV1, bV1, WV2, ws, out);
}

// Round 7
// 202.630 us; speedup vs baseline: 1.3676x; 1.3676x over previous
//
#include <hip/hip_runtime.h>

#define B_TOT 16384
#define NQ 7
#define H 64
#define MD 28
#define GRID (B_TOT/64)   // 256 blocks of 64 = one lane per element

// ws layout (floats), all dim-major [dim][B_TOT], lane-coalesced
#define OFF_A0 0                  // [64][B]   M-net L0 pre-activation
#define OFF_A1 (64*B_TOT)         // float2 [64][B]: (a1, jd1)
#define OFF_R1 (192*B_TOT)        // [64][B]   V-net r1 = WV2 * sig(av1)
#define OFF_SV (256*B_TOT)        // [28][B]   cotangent of x
#define OFF_RP (284*B_TOT)        // [7][B]    tau - Mdot*dq
#define OFF_MI (291*B_TOT)        // [28][B]   Minv (sym packed)
#define OFF_G  (319*B_TOT)        // [7][B]    gravity grad
// total 326*B floats = 21.4 MiB

#define OIDX(hi,lo) ((hi)*((hi)-1)/2 + (lo))

__device__ __forceinline__ float fast_rcp(float x){ return __builtin_amdgcn_rcpf(x); }
__device__ __forceinline__ float sigmoid_f(float a){ return fast_rcp(1.0f + __expf(-a)); }
__device__ __forceinline__ float softplus_f(float a){ return fmaxf(a,0.0f) + __logf(1.0f + __expf(-fabsf(a))); }

// ======== KA: M-net L0 + L1 (value + tangent), all weights via uniform s_load ========
__global__ __launch_bounds__(64) void ka_ml01(
    const float* __restrict__ q, const float* __restrict__ dq,
    const float* __restrict__ WM0, const float* __restrict__ bM0,
    const float* __restrict__ WM1, const float* __restrict__ bM1,
    float* __restrict__ ws)
{
    const int e = blockIdx.x*64 + threadIdx.x;
    float qv[NQ], dqv[NQ];
    #pragma unroll
    for (int d=0; d<NQ; d++){ qv[d]=q[e*NQ+d]; dqv[d]=dq[e*NQ+d]; }

    float z0[H], j0[H];
    #pragma unroll
    for (int o=0;o<H;o++){
        float a=bM0[o], jd=0.0f;
        #pragma unroll
        for (int d=0;d<NQ;d++){ float w=WM0[o*NQ+d]; a=fmaf(w,qv[d],a); jd=fmaf(w,dqv[d],jd); }
        ws[OFF_A0 + o*B_TOT + e] = a;
        z0[o]=softplus_f(a); j0[o]=sigmoid_f(a)*jd;
    }

    float2* a1p = (float2*)(ws + OFF_A1);
    #pragma unroll 2
    for (int o=0;o<H;o++){
        float a=bM1[o], jd=0.0f;
        #pragma unroll
        for (int k=0;k<H;k++){ float w=WM1[o*H+k]; a=fmaf(w,z0[k],a); jd=fmaf(w,j0[k],jd); }
        float2 st; st.x=a; st.y=jd;
        a1p[o*B_TOT + e] = st;
    }
}

// ======== KB: M-net L2 + 7x7 eigen + Loewner products -> sv, rp, Minv ========
__global__ __launch_bounds__(64) void kb_eigen(
    const float* __restrict__ dq, const float* __restrict__ tau,
    const float* __restrict__ WM2, const float* __restrict__ bM2,
    float* __restrict__ ws)
{
    const int e = blockIdx.x*64 + threadIdx.x;

    float x[MD], xd[MD];
    #pragma unroll
    for (int m=0;m<MD;m++){ x[m]=bM2[m]; xd[m]=0.0f; }
    const float2* a1p = (const float2*)(ws + OFF_A1);
    #pragma unroll 2
    for (int o=0;o<H;o++){
        float2 aj = a1p[o*B_TOT + e];
        float s1v = sigmoid_f(aj.x);
        float z1 = softplus_f(aj.x), j1 = s1v*aj.y;
        #pragma unroll
        for (int m=0;m<MD;m++){ float w=WM2[m*H+o]; x[m]=fmaf(w,z1,x[m]); xd[m]=fmaf(w,j1,xd[m]); }
    }

    // Jacobi eigensolver on U=sym(x)
    float Ad[NQ], Ao[21], V[49];
    #pragma unroll
    for (int i=0;i<NQ;i++) Ad[i]=x[i];
    #pragma unroll
    for (int t=0;t<21;t++) Ao[t]=x[NQ+t];
    #pragma unroll
    for (int t=0;t<49;t++) V[t]=0.0f;
    #pragma unroll
    for (int i=0;i<NQ;i++) V[i*7+i]=1.0f;

    #pragma unroll 1
    for (int sweep=0; sweep<6; sweep++){
        #pragma unroll
        for (int p=0;p<6;p++){
            #pragma unroll
            for (int qq=p+1;qq<7;qq++){
                float app=Ad[p], aqq=Ad[qq], apq=Ao[OIDX(qq,p)];
                bool rot = fabsf(apq) > 1e-20f;
                float apq_s = rot ? apq : 1.0f;
                float theta = (aqq-app) * fast_rcp(2.0f*apq_s);
                float t = fast_rcp(fabsf(theta)+sqrtf(fmaf(theta,theta,1.0f)));
                t = (theta<0.0f)? -t : t;
                t = rot ? t : 0.0f;
                float c = rsqrtf(fmaf(t,t,1.0f));
                float s = t*c;
                #pragma unroll
                for (int j=0;j<7;j++){
                    if (j==p || j==qq) continue;
                    float ajp = (j<p)?  Ao[OIDX(p,j)]  : Ao[OIDX(j,p)];
                    float ajq = (j<qq)? Ao[OIDX(qq,j)] : Ao[OIDX(j,qq)];
                    float np_ = fmaf(c,ajp,-s*ajq);
                    float nq_ = fmaf(s,ajp, c*ajq);
                    if (j<p)  Ao[OIDX(p,j)]  = np_; else Ao[OIDX(j,p)]  = np_;
                    if (j<qq) Ao[OIDX(qq,j)] = nq_; else Ao[OIDX(j,qq)] = nq_;
                }
                Ad[p]  = fmaf(-t,apq,app);
                Ad[qq] = fmaf( t,apq,aqq);
                Ao[OIDX(qq,p)] = 0.0f;
                #pragma unroll
                for (int j=0;j<7;j++){
                    float vp=V[j*7+p], vq=V[j*7+qq];
                    V[j*7+p]  = fmaf(c,vp,-s*vq);
                    V[j*7+qq] = fmaf(s,vp, c*vq);
                }
            }
        }
    }

    float ee[7], iee[7];
    #pragma unroll
    for (int i=0;i<7;i++){ ee[i]=__expf(Ad[i]); iee[i]=fast_rcp(ee[i]); }

    float Ro[21];
    #pragma unroll
    for (int p=0;p<6;p++){
        #pragma unroll
        for (int qj=p+1;qj<7;qj++){
            float d = Ad[p]-Ad[qj];
            bool big = fabsf(d) > 1e-3f;
            float den = big ? d : 1.0f;
            float exact = (ee[p]-ee[qj])*fast_rcp(den);
            float ser = sqrtf(ee[p]*ee[qj]) * fmaf(d*d,(1.0f/24.0f),1.0f);
            Ro[OIDX(qj,p)] = big ? exact : ser;
        }
    }

    float dqv[7], tv[7];
    #pragma unroll
    for (int d=0;d<7;d++){ dqv[d]=dq[e*NQ+d]; tv[d]=tau[e*NQ+d]; }

    float w[7];
    #pragma unroll
    for (int a=0;a<7;a++){
        float acc=0.0f;
        #pragma unroll
        for (int j=0;j<7;j++) acc=fmaf(V[j*7+a],dqv[j],acc);
        w[a]=acc;
    }

    // sv = cotangent: S = V (R o wwT) V^T, offdiag doubled
    {
        float Yd[7], Yo[21];
        #pragma unroll
        for (int a=0;a<7;a++) Yd[a]=ee[a]*w[a]*w[a];
        #pragma unroll
        for (int p=0;p<6;p++){
            #pragma unroll
            for (int qj=p+1;qj<7;qj++) Yo[OIDX(qj,p)]=Ro[OIDX(qj,p)]*w[p]*w[qj];
        }
        float P[49];
        #pragma unroll
        for (int i=0;i<7;i++){
            #pragma unroll
            for (int a=0;a<7;a++){
                float acc=0.0f;
                #pragma unroll
                for (int c=0;c<7;c++){
                    float y=(c==a)? Yd[a] : ((c<a)? Yo[OIDX(a,c)] : Yo[OIDX(c,a)]);
                    acc=fmaf(V[i*7+c],y,acc);
                }
                P[i*7+a]=acc;
            }
        }
        #pragma unroll
        for (int i=0;i<7;i++){
            #pragma unroll
            for (int j=i;j<7;j++){
                float acc=0.0f;
                #pragma unroll
                for (int a=0;a<7;a++) acc=fmaf(P[i*7+a],V[j*7+a],acc);
                if (i==j) ws[OFF_SV + i*B_TOT + e]=acc;
                else      ws[OFF_SV + (NQ+OIDX(j,i))*B_TOT + e]=2.0f*acc;
            }
        }
    }

    // rp = tau - V (R o (V^T Udot V)) V^T dq
    {
        float P2[49];
        #pragma unroll
        for (int i=0;i<7;i++){
            #pragma unroll
            for (int a=0;a<7;a++){
                float acc=0.0f;
                #pragma unroll
                for (int j=0;j<7;j++){
                    float u=(i==j)? xd[i] : ((j<i)? xd[NQ+OIDX(i,j)] : xd[NQ+OIDX(j,i)]);
                    acc=fmaf(u,V[j*7+a],acc);
                }
                P2[i*7+a]=acc;
            }
        }
        float Td[7], To[21];
        #pragma unroll
        for (int a=0;a<7;a++){
            float acc=0.0f;
            #pragma unroll
            for (int i=0;i<7;i++) acc=fmaf(V[i*7+a],P2[i*7+a],acc);
            Td[a]=acc;
        }
        #pragma unroll
        for (int a=0;a<6;a++){
            #pragma unroll
            for (int bb=a+1;bb<7;bb++){
                float acc=0.0f;
                #pragma unroll
                for (int i=0;i<7;i++) acc=fmaf(V[i*7+a],P2[i*7+bb],acc);
                To[OIDX(bb,a)]=acc;
            }
        }
        float zw[7];
        #pragma unroll
        for (int a=0;a<7;a++){
            float acc=ee[a]*Td[a]*w[a];
            #pragma unroll
            for (int bb=0;bb<7;bb++){
                if (bb==a) continue;
                float z=(bb<a)? (Ro[OIDX(a,bb)]*To[OIDX(a,bb)]) : (Ro[OIDX(bb,a)]*To[OIDX(bb,a)]);
                acc=fmaf(z,w[bb],acc);
            }
            zw[a]=acc;
        }
        #pragma unroll
        for (int i=0;i<7;i++){
            float acc=0.0f;
            #pragma unroll
            for (int a=0;a<7;a++) acc=fmaf(V[i*7+a],zw[a],acc);
            ws[OFF_RP + i*B_TOT + e] = tv[i]-acc;
        }
    }

    // Minv = V diag(1/ee) V^T
    #pragma unroll
    for (int i=0;i<7;i++){
        #pragma unroll
        for (int j=i;j<7;j++){
            float acc=0.0f;
            #pragma unroll
            for (int a=0;a<7;a++) acc=fmaf(V[i*7+a]*iee[a],V[j*7+a],acc);
            if (i==j) ws[OFF_MI + i*B_TOT + e]=acc;
            else      ws[OFF_MI + (NQ+OIDX(j,i))*B_TOT + e]=acc;
        }
    }
}

// ======== KC1: V-net L0 + L1 forward -> r1 ========
__global__ __launch_bounds__(64) void kc1_vfwd(
    const float* __restrict__ q,
    const float* __restrict__ WV0, const float* __restrict__ bV0,
    const float* __restrict__ WV1, const float* __restrict__ bV1,
    const float* __restrict__ WV2,
    float* __restrict__ ws)
{
    const int e = blockIdx.x*64 + threadIdx.x;
    float qv[NQ];
    #pragma unroll
    for (int d=0; d<NQ; d++) qv[d]=q[e*NQ+d];

    float zv0[H];
    #pragma unroll
    for (int o=0;o<H;o++){
        float a=bV0[o];
        #pragma unroll
        for (int d=0;d<NQ;d++) a=fmaf(WV0[o*NQ+d],qv[d],a);
        zv0[o]=softplus_f(a);
    }
    #pragma unroll 2
    for (int o=0;o<H;o++){
        float a=bV1[o];
        #pragma unroll
        for (int k=0;k<H;k++) a=fmaf(WV1[o*H+k],zv0[k],a);
        ws[OFF_R1 + o*B_TOT + e] = WV2[o]*sigmoid_f(a);
    }
}

// ======== KC2: V-net reverse -> g ========
__global__ __launch_bounds__(64) void kc2_vrev(
    const float* __restrict__ q,
    const float* __restrict__ WV0, const float* __restrict__ bV0,
    const float* __restrict__ WV1,
    float* __restrict__ ws)
{
    const int e = blockIdx.x*64 + threadIdx.x;
    float qv[NQ];
    #pragma unroll
    for (int d=0; d<NQ; d++) qv[d]=q[e*NQ+d];

    float r1[H];
    #pragma unroll
    for (int o=0;o<H;o++) r1[o]=ws[OFF_R1 + o*B_TOT + e];

    float g[NQ];
    #pragma unroll
    for (int d=0;d<NQ;d++) g[d]=0.0f;

    #pragma unroll 2
    for (int k=0;k<H;k++){
        float racc=0.0f;
        #pragma unroll
        for (int o=0;o<H;o++) racc=fmaf(WV1[o*H+k],r1[o],racc);
        float av0=bV0[k];
        #pragma unroll
        for (int d=0;d<NQ;d++) av0=fmaf(WV0[k*NQ+d],qv[d],av0);
        float r0f = sigmoid_f(av0)*racc;
        #pragma unroll
        for (int d=0;d<NQ;d++) g[d]=fmaf(WV0[k*NQ+d],r0f,g[d]);
    }
    #pragma unroll
    for (int d=0;d<NQ;d++) ws[OFF_G + d*B_TOT + e]=g[d];
}

// ======== KD: M-net reverse (s), rhs, SPD solve -> out ========
__global__ __launch_bounds__(64) void kd_solve(
    const float* __restrict__ WM0, const float* __restrict__ WM1, const float* __restrict__ WM2,
    const float* __restrict__ ws,
    float* __restrict__ out)
{
    const int e = blockIdx.x*64 + threadIdx.x;

    float sv[MD];
    #pragma unroll
    for (int m=0;m<MD;m++) sv[m]=ws[OFF_SV + m*B_TOT + e];

    const float2* a1p = (const float2*)(ws + OFF_A1);
    float rr1f[H];
    #pragma unroll 2
    for (int k=0;k<H;k++){
        float acc=0.0f;
        #pragma unroll
        for (int m=0;m<MD;m++) acc=fmaf(WM2[m*H+k],sv[m],acc);
        float a1k = a1p[k*B_TOT + e].x;
        rr1f[k] = sigmoid_f(a1k)*acc;
    }

    float sacc[NQ];
    #pragma unroll
    for (int d=0;d<NQ;d++) sacc[d]=0.0f;
    #pragma unroll 2
    for (int k=0;k<H;k++){
        float a2=0.0f;
        #pragma unroll
        for (int i=0;i<H;i++) a2=fmaf(WM1[i*H+k],rr1f[i],a2);
        float a0k = ws[OFF_A0 + k*B_TOT + e];
        float tk = sigmoid_f(a0k)*a2;
        #pragma unroll
        for (int d=0;d<NQ;d++) sacc[d]=fmaf(WM0[k*NQ+d],tk,sacc[d]);
    }

    float rhs[NQ];
    #pragma unroll
    for (int d=0;d<NQ;d++)
        rhs[d] = ws[OFF_RP + d*B_TOT + e] + 0.5f*sacc[d] - ws[OFF_G + d*B_TOT + e];

    float mi[MD];
    #pragma unroll
    for (int t=0;t<MD;t++) mi[t]=ws[OFF_MI + t*B_TOT + e];

    #pragma unroll
    for (int i=0;i<NQ;i++){
        float acc=0.0f;
        #pragma unroll
        for (int j=0;j<NQ;j++){
            int idx=(j==i)? i : (NQ + ((j>i)? OIDX(j,i) : OIDX(i,j)));
            acc=fmaf(mi[idx],rhs[j],acc);
        }
        out[e*NQ+i]=acc;
    }
}

extern "C" void kernel_launch(void* const* d_in, const int* in_sizes, int n_in,
                              void* d_out, int out_size, void* d_ws, size_t ws_size,
                              hipStream_t stream) {
    const float* q   = (const float*)d_in[0];
    const float* dq  = (const float*)d_in[1];
    const float* tau = (const float*)d_in[2];
    const float* WM0 = (const float*)d_in[3];
    const float* bM0 = (const float*)d_in[4];
    const float* WM1 = (const float*)d_in[5];
    const float* bM1 = (const float*)d_in[6];
    const float* WM2 = (const float*)d_in[7];
    const float* bM2 = (const float*)d_in[8];
    const float* WV0 = (const float*)d_in[9];
    const float* bV0 = (const float*)d_in[10];
    const float* WV1 = (const float*)d_in[11];
    const float* bV1 = (const float*)d_in[12];
    const float* WV2 = (const float*)d_in[13];
    float* ws  = (float*)d_ws;
    float* out = (float*)d_out;

    hipLaunchKernelGGL(ka_ml01,  dim3(GRID), dim3(64), 0, stream, q, dq, WM0, bM0, WM1, bM1, ws);
    hipLaunchKernelGGL(kb_eigen, dim3(GRID), dim3(64), 0, stream, dq, tau, WM2, bM2, ws);
    hipLaunchKernelGGL(kc1_vfwd, dim3(GRID), dim3(64), 0, stream, q, WV0, bV0, WV1, bV1, WV2, ws);
    hipLaunchKernelGGL(kc2_vrev, dim3(GRID), dim3(64), 0, stream, q, WV0, bV0, WV1, ws);
    hipLaunchKernelGGL(kd_solve, dim3(GRID), dim3(64), 0, stream, WM0, WM1, WM2, ws, out);
}

// Round 8
// 103.469 us; speedup vs baseline: 2.6783x; 1.9584x over previous
//
#include <hip/hip_runtime.h>

#define B_TOT 16384
#define NQ 7
#define H 64
#define MD 28
#define GRID (B_TOT/64)

// ws layout (floats), dim-major [dim][B_TOT], lane-coalesced
#define OFF_A0 0               // [64][B] M-net L0 pre-act
#define OFF_A1 (64*B_TOT)      // [64][B] M-net L1 pre-act
#define OFF_X  (128*B_TOT)     // [28][B]
#define OFF_XD (156*B_TOT)     // [28][B]
#define OFF_SV (184*B_TOT)     // [28][B]
#define OFF_RP (212*B_TOT)     // [7][B]
#define OFF_MI (219*B_TOT)     // [28][B]
#define OFF_G  (247*B_TOT)     // [7][B]  -> total 254*B = 16.6 MiB

#define OIDX(hi,lo) ((hi)*((hi)-1)/2 + (lo))

__device__ __forceinline__ float fast_rcp(float x){ return __builtin_amdgcn_rcpf(x); }
__device__ __forceinline__ float sigmoid_f(float a){ return fast_rcp(1.0f + __expf(-a)); }
__device__ __forceinline__ float softplus_f(float a){ return fmaxf(a,0.0f) + __logf(1.0f + __expf(-fabsf(a))); }

// ======== KA: M-net L0 + L1 (+JVP) + L2 partials; 4 waves split H ========
__global__ __launch_bounds__(256) void ka_mnet(
    const float* __restrict__ q, const float* __restrict__ dq,
    const float* __restrict__ WM0, const float* __restrict__ bM0,
    const float* __restrict__ WM1, const float* __restrict__ bM1,
    const float* __restrict__ WM2, const float* __restrict__ bM2,
    float* __restrict__ ws)
{
    __shared__ float w2ts[H*29];        // w2ts[o][m] = WM2[m*H+o], pad 29
    __shared__ float red[3][56][64];    // partial x/xd from waves 1..3
    const int tid = threadIdx.x, lane = tid&63, wid = tid>>6;
    for (int t=tid; t<MD*H; t+=256){ int m=t>>6, o=t&63; w2ts[o*29+m]=WM2[t]; }

    const int e = blockIdx.x*64 + lane;
    float qv[NQ], dqv[NQ];
    #pragma unroll
    for (int d=0; d<NQ; d++){ qv[d]=q[e*NQ+d]; dqv[d]=dq[e*NQ+d]; }

    // L0 (all o, redundant per wave; each wave stores its o-slice of a0)
    float z0[H], j0[H];
    #pragma unroll
    for (int o=0;o<H;o++){
        float a=bM0[o], jd=0.0f;
        #pragma unroll
        for (int d=0;d<NQ;d++){ float w=WM0[o*NQ+d]; a=fmaf(w,qv[d],a); jd=fmaf(w,dqv[d],jd); }
        if ((o>>4)==wid) ws[OFF_A0 + o*B_TOT + e] = a;
        z0[o]=softplus_f(a); j0[o]=sigmoid_f(a)*jd;
    }
    __syncthreads();   // w2ts ready

    // L1 for o-slice + L2 partial accumulation
    float xp[MD], xdp[MD];
    #pragma unroll
    for (int m=0;m<MD;m++){ xp[m] = (wid==0)? bM2[m] : 0.0f; xdp[m]=0.0f; }
    #pragma unroll 1
    for (int oo=0;oo<16;oo++){
        const int o=(wid<<4)+oo;
        float a=bM1[o], jd=0.0f;
        #pragma unroll
        for (int k=0;k<H;k++){ float w=WM1[o*H+k]; a=fmaf(w,z0[k],a); jd=fmaf(w,j0[k],jd); }
        ws[OFF_A1 + o*B_TOT + e] = a;
        float s1=sigmoid_f(a), z1=softplus_f(a), j1=s1*jd;
        #pragma unroll
        for (int m=0;m<MD;m++){ float w=w2ts[o*29+m]; xp[m]=fmaf(w,z1,xp[m]); xdp[m]=fmaf(w,j1,xdp[m]); }
    }

    if (wid>0){
        #pragma unroll
        for (int m=0;m<MD;m++){ red[wid-1][m][lane]=xp[m]; red[wid-1][MD+m][lane]=xdp[m]; }
    }
    __syncthreads();
    if (wid==0){
        #pragma unroll
        for (int w=0;w<3;w++){
            #pragma unroll
            for (int m=0;m<MD;m++){ xp[m]+=red[w][m][lane]; xdp[m]+=red[w][MD+m][lane]; }
        }
        #pragma unroll
        for (int m=0;m<MD;m++){ ws[OFF_X+m*B_TOT+e]=xp[m]; ws[OFF_XD+m*B_TOT+e]=xdp[m]; }
    }
}

// ======== KB: 7x7 eigen + Loewner -> sv, rp, Minv (serial per lane) ========
__global__ __launch_bounds__(64) void kb_eigen(
    const float* __restrict__ dq, const float* __restrict__ tau,
    float* __restrict__ ws)
{
    const int e = blockIdx.x*64 + threadIdx.x;

    float x[MD], xd[MD];
    #pragma unroll
    for (int m=0;m<MD;m++){ x[m]=ws[OFF_X+m*B_TOT+e]; xd[m]=ws[OFF_XD+m*B_TOT+e]; }

    float Ad[NQ], Ao[21], V[49];
    #pragma unroll
    for (int i=0;i<NQ;i++) Ad[i]=x[i];
    #pragma unroll
    for (int t=0;t<21;t++) Ao[t]=x[NQ+t];
    #pragma unroll
    for (int t=0;t<49;t++) V[t]=0.0f;
    #pragma unroll
    for (int i=0;i<NQ;i++) V[i*7+i]=1.0f;

    #pragma unroll 1
    for (int sweep=0; sweep<6; sweep++){
        #pragma unroll
        for (int p=0;p<6;p++){
            #pragma unroll
            for (int qq=p+1;qq<7;qq++){
                float app=Ad[p], aqq=Ad[qq], apq=Ao[OIDX(qq,p)];
                bool rot = fabsf(apq) > 1e-20f;
                float apq_s = rot ? apq : 1.0f;
                float theta = (aqq-app) * fast_rcp(2.0f*apq_s);
                float t = fast_rcp(fabsf(theta)+sqrtf(fmaf(theta,theta,1.0f)));
                t = (theta<0.0f)? -t : t;
                t = rot ? t : 0.0f;
                float c = rsqrtf(fmaf(t,t,1.0f));
                float s = t*c;
                #pragma unroll
                for (int j=0;j<7;j++){
                    if (j==p || j==qq) continue;
                    float ajp = (j<p)?  Ao[OIDX(p,j)]  : Ao[OIDX(j,p)];
                    float ajq = (j<qq)? Ao[OIDX(qq,j)] : Ao[OIDX(j,qq)];
                    float np_ = fmaf(c,ajp,-s*ajq);
                    float nq_ = fmaf(s,ajp, c*ajq);
                    if (j<p)  Ao[OIDX(p,j)]  = np_; else Ao[OIDX(j,p)]  = np_;
                    if (j<qq) Ao[OIDX(qq,j)] = nq_; else Ao[OIDX(j,qq)] = nq_;
                }
                Ad[p]  = fmaf(-t,apq,app);
                Ad[qq] = fmaf( t,apq,aqq);
                Ao[OIDX(qq,p)] = 0.0f;
                #pragma unroll
                for (int j=0;j<7;j++){
                    float vp=V[j*7+p], vq=V[j*7+qq];
                    V[j*7+p]  = fmaf(c,vp,-s*vq);
                    V[j*7+qq] = fmaf(s,vp, c*vq);
                }
            }
        }
    }

    float ee[7], iee[7];
    #pragma unroll
    for (int i=0;i<7;i++){ ee[i]=__expf(Ad[i]); iee[i]=fast_rcp(ee[i]); }

    float Ro[21];
    #pragma unroll
    for (int p=0;p<6;p++){
        #pragma unroll
        for (int qj=p+1;qj<7;qj++){
            float d = Ad[p]-Ad[qj];
            bool big = fabsf(d) > 1e-3f;
            float den = big ? d : 1.0f;
            float exact = (ee[p]-ee[qj])*fast_rcp(den);
            float ser = sqrtf(ee[p]*ee[qj]) * fmaf(d*d,(1.0f/24.0f),1.0f);
            Ro[OIDX(qj,p)] = big ? exact : ser;
        }
    }

    float dqv[7], tv[7];
    #pragma unroll
    for (int d=0;d<7;d++){ dqv[d]=dq[e*NQ+d]; tv[d]=tau[e*NQ+d]; }

    float w[7];
    #pragma unroll
    for (int a=0;a<7;a++){
        float acc=0.0f;
        #pragma unroll
        for (int j=0;j<7;j++) acc=fmaf(V[j*7+a],dqv[j],acc);
        w[a]=acc;
    }

    // sv cotangent: S = V (R o wwT) V^T, offdiag doubled
    {
        float Yd[7], Yo[21];
        #pragma unroll
        for (int a=0;a<7;a++) Yd[a]=ee[a]*w[a]*w[a];
        #pragma unroll
        for (int p=0;p<6;p++){
            #pragma unroll
            for (int qj=p+1;qj<7;qj++) Yo[OIDX(qj,p)]=Ro[OIDX(qj,p)]*w[p]*w[qj];
        }
        float P[49];
        #pragma unroll
        for (int i=0;i<7;i++){
            #pragma unroll
            for (int a=0;a<7;a++){
                float acc=0.0f;
                #pragma unroll
                for (int c=0;c<7;c++){
                    float y=(c==a)? Yd[a] : ((c<a)? Yo[OIDX(a,c)] : Yo[OIDX(c,a)]);
                    acc=fmaf(V[i*7+c],y,acc);
                }
                P[i*7+a]=acc;
            }
        }
        #pragma unroll
        for (int i=0;i<7;i++){
            #pragma unroll
            for (int j=i;j<7;j++){
                float acc=0.0f;
                #pragma unroll
                for (int a=0;a<7;a++) acc=fmaf(P[i*7+a],V[j*7+a],acc);
                if (i==j) ws[OFF_SV + i*B_TOT + e]=acc;
                else      ws[OFF_SV + (NQ+OIDX(j,i))*B_TOT + e]=2.0f*acc;
            }
        }
    }

    // rp = tau - V (R o (V^T Udot V)) V^T dq
    {
        float P2[49];
        #pragma unroll
        for (int i=0;i<7;i++){
            #pragma unroll
            for (int a=0;a<7;a++){
                float acc=0.0f;
                #pragma unroll
                for (int j=0;j<7;j++){
                    float u=(i==j)? xd[i] : ((j<i)? xd[NQ+OIDX(i,j)] : xd[NQ+OIDX(j,i)]);
                    acc=fmaf(u,V[j*7+a],acc);
                }
                P2[i*7+a]=acc;
            }
        }
        float Td[7], To[21];
        #pragma unroll
        for (int a=0;a<7;a++){
            float acc=0.0f;
            #pragma unroll
            for (int i=0;i<7;i++) acc=fmaf(V[i*7+a],P2[i*7+a],acc);
            Td[a]=acc;
        }
        #pragma unroll
        for (int a=0;a<6;a++){
            #pragma unroll
            for (int bb=a+1;bb<7;bb++){
                float acc=0.0f;
                #pragma unroll
                for (int i=0;i<7;i++) acc=fmaf(V[i*7+a],P2[i*7+bb],acc);
                To[OIDX(bb,a)]=acc;
            }
        }
        float zw[7];
        #pragma unroll
        for (int a=0;a<7;a++){
            float acc=ee[a]*Td[a]*w[a];
            #pragma unroll
            for (int bb=0;bb<7;bb++){
                if (bb==a) continue;
                float z=(bb<a)? (Ro[OIDX(a,bb)]*To[OIDX(a,bb)]) : (Ro[OIDX(bb,a)]*To[OIDX(bb,a)]);
                acc=fmaf(z,w[bb],acc);
            }
            zw[a]=acc;
        }
        #pragma unroll
        for (int i=0;i<7;i++){
            float acc=0.0f;
            #pragma unroll
            for (int a=0;a<7;a++) acc=fmaf(V[i*7+a],zw[a],acc);
            ws[OFF_RP + i*B_TOT + e] = tv[i]-acc;
        }
    }

    // Minv = V diag(1/ee) V^T
    #pragma unroll
    for (int i=0;i<7;i++){
        #pragma unroll
        for (int j=i;j<7;j++){
            float acc=0.0f;
            #pragma unroll
            for (int a=0;a<7;a++) acc=fmaf(V[i*7+a]*iee[a],V[j*7+a],acc);
            if (i==j) ws[OFF_MI + i*B_TOT + e]=acc;
            else      ws[OFF_MI + (NQ+OIDX(j,i))*B_TOT + e]=acc;
        }
    }
}

// ======== KC: V-net fwd + reverse -> g; 4 waves split H ========
__global__ __launch_bounds__(256) void kc_vnet(
    const float* __restrict__ q,
    const float* __restrict__ WV0, const float* __restrict__ bV0,
    const float* __restrict__ WV1, const float* __restrict__ bV1,
    const float* __restrict__ WV2,
    float* __restrict__ ws)
{
    __shared__ float wv1t[H*65];     // [k][o] = WV1[o*H+k], pad 65
    __shared__ float r1s[H*64];      // [o][lane]
    __shared__ float gred[3][8][64];
    const int tid=threadIdx.x, lane=tid&63, wid=tid>>6;
    for (int t=tid; t<H*H; t+=256){ int o=t>>6, k=t&63; wv1t[k*65+o]=WV1[t]; }

    const int e = blockIdx.x*64 + lane;
    float qv[NQ];
    #pragma unroll
    for (int d=0; d<NQ; d++) qv[d]=q[e*NQ+d];
    __syncthreads();

    // L0 (all o, redundant); keep pre-act for own k-slice
    float zv0[H], av0s[16];
    #pragma unroll
    for (int o=0;o<H;o++){
        float a=bV0[o];
        #pragma unroll
        for (int d=0;d<NQ;d++) a=fmaf(WV0[o*NQ+d],qv[d],a);
        zv0[o]=softplus_f(a);
        if ((o>>4)==wid) av0s[o&15]=a;
    }

    // L1 fwd for o-slice -> r1 into LDS
    #pragma unroll 1
    for (int oo=0;oo<16;oo++){
        const int o=(wid<<4)+oo;
        float a=bV1[o];
        #pragma unroll
        for (int k=0;k<H;k++) a=fmaf(wv1t[k*65+o], zv0[k], a);
        r1s[o*64+lane] = WV2[o]*sigmoid_f(a);
    }
    __syncthreads();

    // reverse: k-slice
    float gp[NQ];
    #pragma unroll
    for (int d=0;d<NQ;d++) gp[d]=0.0f;
    #pragma unroll 1
    for (int kk=0;kk<16;kk++){
        const int k=(wid<<4)+kk;
        float racc=0.0f;
        #pragma unroll
        for (int o=0;o<H;o++) racc=fmaf(wv1t[k*65+o], r1s[o*64+lane], racc);
        float r0f = sigmoid_f(av0s[kk])*racc;
        #pragma unroll
        for (int d=0;d<NQ;d++) gp[d]=fmaf(WV0[k*NQ+d], r0f, gp[d]);
    }

    if (wid>0){
        #pragma unroll
        for (int d=0;d<NQ;d++) gred[wid-1][d][lane]=gp[d];
    }
    __syncthreads();
    if (wid==0){
        #pragma unroll
        for (int w=0;w<3;w++){
            #pragma unroll
            for (int d=0;d<NQ;d++) gp[d]+=gred[w][d][lane];
        }
        #pragma unroll
        for (int d=0;d<NQ;d++) ws[OFF_G + d*B_TOT + e]=gp[d];
    }
}

// ======== KD: M-net reverse (s), rhs, SPD solve -> out; 4 waves split H ========
__global__ __launch_bounds__(256) void kd_solve(
    const float* __restrict__ WM0, const float* __restrict__ WM1, const float* __restrict__ WM2,
    const float* __restrict__ ws,
    float* __restrict__ out)
{
    __shared__ float w1ts[H*65];     // [k][i] = WM1[i*H+k]
    __shared__ float w2ts[H*29];     // [k][m] = WM2[m*H+k]
    __shared__ float rr1fs[H*64];    // [k][lane]
    __shared__ float sred[3][8][64];
    const int tid=threadIdx.x, lane=tid&63, wid=tid>>6;
    for (int t=tid; t<H*H; t+=256){ int i=t>>6, k=t&63; w1ts[k*65+i]=WM1[t]; }
    for (int t=tid; t<MD*H; t+=256){ int m=t>>6, k=t&63; w2ts[k*29+m]=WM2[t]; }

    const int e = blockIdx.x*64 + lane;
    float sv[MD];
    #pragma unroll
    for (int m=0;m<MD;m++) sv[m]=ws[OFF_SV + m*B_TOT + e];
    __syncthreads();

    // phase1: rr1f for k-slice
    #pragma unroll 1
    for (int kk=0;kk<16;kk++){
        const int k=(wid<<4)+kk;
        float acc=0.0f;
        #pragma unroll
        for (int m=0;m<MD;m++) acc=fmaf(w2ts[k*29+m], sv[m], acc);
        float a1k=ws[OFF_A1 + k*B_TOT + e];
        rr1fs[k*64+lane]=sigmoid_f(a1k)*acc;
    }
    __syncthreads();

    // phase2: s partials for k'-slice
    float sp[NQ];
    #pragma unroll
    for (int d=0;d<NQ;d++) sp[d]=0.0f;
    #pragma unroll 1
    for (int kk=0;kk<16;kk++){
        const int k=(wid<<4)+kk;
        float t2=0.0f;
        #pragma unroll
        for (int i=0;i<H;i++) t2=fmaf(w1ts[k*65+i], rr1fs[i*64+lane], t2);
        float a0k=ws[OFF_A0 + k*B_TOT + e];
        float tkv=sigmoid_f(a0k)*t2;
        #pragma unroll
        for (int d=0;d<NQ;d++) sp[d]=fmaf(WM0[k*NQ+d], tkv, sp[d]);
    }

    if (wid>0){
        #pragma unroll
        for (int d=0;d<NQ;d++) sred[wid-1][d][lane]=sp[d];
    }
    __syncthreads();
    if (wid==0){
        #pragma unroll
        for (int w=0;w<3;w++){
            #pragma unroll
            for (int d=0;d<NQ;d++) sp[d]+=sred[w][d][lane];
        }
        float rhs[NQ], mi[MD];
        #pragma unroll
        for (int d=0;d<NQ;d++)
            rhs[d] = ws[OFF_RP + d*B_TOT + e] + 0.5f*sp[d] - ws[OFF_G + d*B_TOT + e];
        #pragma unroll
        for (int t=0;t<MD;t++) mi[t]=ws[OFF_MI + t*B_TOT + e];
        #pragma unroll
        for (int i=0;i<NQ;i++){
            float acc=0.0f;
            #pragma unroll
            for (int j=0;j<NQ;j++){
                int idx=(j==i)? i : (NQ + ((j>i)? OIDX(j,i) : OIDX(i,j)));
                acc=fmaf(mi[idx],rhs[j],acc);
            }
            out[e*NQ+i]=acc;
        }
    }
}

extern "C" void kernel_launch(void* const* d_in, const int* in_sizes, int n_in,
                              void* d_out, int out_size, void* d_ws, size_t ws_size,
                              hipStream_t stream) {
    const float* q   = (const float*)d_in[0];
    const float* dq  = (const float*)d_in[1];
    const float* tau = (const float*)d_in[2];
    const float* WM0 = (const float*)d_in[3];
    const float* bM0 = (const float*)d_in[4];
    const float* WM1 = (const float*)d_in[5];
    const float* bM1 = (const float*)d_in[6];
    const float* WM2 = (const float*)d_in[7];
    const float* bM2 = (const float*)d_in[8];
    const float* WV0 = (const float*)d_in[9];
    const float* bV0 = (const float*)d_in[10];
    const float* WV1 = (const float*)d_in[11];
    const float* bV1 = (const float*)d_in[12];
    const float* WV2 = (const float*)d_in[13];
    float* ws  = (float*)d_ws;
    float* out = (float*)d_out;

    hipLaunchKernelGGL(ka_mnet,  dim3(GRID), dim3(256), 0, stream, q, dq, WM0, bM0, WM1, bM1, WM2, bM2, ws);
    hipLaunchKernelGGL(kb_eigen, dim3(GRID), dim3(64),  0, stream, dq, tau, ws);
    hipLaunchKernelGGL(kc_vnet,  dim3(GRID), dim3(256), 0, stream, q, WV0, bV0, WV1, bV1, WV2, ws);
    hipLaunchKernelGGL(kd_solve, dim3(GRID), dim3(256), 0, stream, WM0, WM1, WM2, ws, out);
}

// Round 9
// 71.669 us; speedup vs baseline: 3.8667x; 1.4437x over previous
//
#include <hip/hip_runtime.h>

#define B_TOT 16384
#define NQ 7
#define H 64
#define MD 28

// ws layout (floats), dim-major [dim][B_TOT], lane-coalesced (same as R8)
#define OFF_A0 0               // [64][B] M-net L0 pre-act
#define OFF_A1 (64*B_TOT)      // [64][B] M-net L1 pre-act
#define OFF_X  (128*B_TOT)     // [28][B]
#define OFF_XD (156*B_TOT)     // [28][B]
#define OFF_SV (184*B_TOT)     // [28][B]
#define OFF_RP (212*B_TOT)     // [7][B]
#define OFF_MI (219*B_TOT)     // [28][B]
#define OFF_G  (247*B_TOT)     // [7][B]

#define OIDX(hi,lo) ((hi)*((hi)-1)/2 + (lo))

__device__ __forceinline__ float fast_rcp(float x){ return __builtin_amdgcn_rcpf(x); }
__device__ __forceinline__ float sigmoid_f(float a){ return fast_rcp(1.0f + __expf(-a)); }
__device__ __forceinline__ float softplus_f(float a){ return fmaxf(a,0.0f) + __logf(1.0f + __expf(-fabsf(a))); }

// ==== K_FWD: blocks 0..255 = M-net fwd+JVP; blocks 256..511 = V-net fwd+rev (g) ====
__global__ __launch_bounds__(512) void k_fwd(
    const float* __restrict__ q, const float* __restrict__ dq,
    const float* __restrict__ WM0, const float* __restrict__ bM0,
    const float* __restrict__ WM1, const float* __restrict__ bM1,
    const float* __restrict__ WM2, const float* __restrict__ bM2,
    const float* __restrict__ WV0, const float* __restrict__ bV0,
    const float* __restrict__ WV1, const float* __restrict__ bV1,
    const float* __restrict__ WV2,
    float* __restrict__ ws)
{
    __shared__ __align__(16) char smem[65536];
    const int tid=threadIdx.x, lane=tid&63, wid=tid>>6;

    if ((int)blockIdx.x < 256) {
        // ---------------- M-net path ----------------
        float2* zj  = (float2*)smem;          // [k][lane] (z, jvp) 32 KB
        float*  w1t = (float*)(smem+32768);   // [k][o] transposed WM1, 16 KB
        float*  w2t = (float*)(smem+49152);   // [k][m] transposed WM2, 7 KB
        const int e = blockIdx.x*64 + lane;

        float qv[NQ], dqv[NQ];
        #pragma unroll
        for (int d=0;d<NQ;d++){ qv[d]=q[e*NQ+d]; dqv[d]=dq[e*NQ+d]; }

        for (int t=tid; t<H*H; t+=512)  w1t[(t&63)*H  + (t>>6)] = WM1[t];
        for (int t=tid; t<MD*H; t+=512) w2t[(t&63)*MD + (t>>6)] = WM2[t];

        // stage A: L0 for o-slice [8*wid, 8*wid+8)
        #pragma unroll
        for (int oo=0;oo<8;oo++){
            const int o = wid*8+oo;
            float a=bM0[o], jd=0.f;
            #pragma unroll
            for (int d=0;d<NQ;d++){ float w=WM0[o*NQ+d]; a=fmaf(w,qv[d],a); jd=fmaf(w,dqv[d],jd); }
            ws[OFF_A0 + o*B_TOT + e] = a;
            zj[o*64+lane] = make_float2(softplus_f(a), sigmoid_f(a)*jd);
        }
        __syncthreads();

        // stage B: L1 for o-slice, k-outer (1 ds_b64 + 2x b128 weight bcast + 16 fma per k)
        float a1[8], jd1[8];
        #pragma unroll
        for (int oo=0;oo<8;oo++){ a1[oo]=bM1[wid*8+oo]; jd1[oo]=0.f; }
        #pragma unroll 4
        for (int k=0;k<H;k++){
            float2 z = zj[k*64+lane];
            float wv[8];
            *(float4*)&wv[0] = *(const float4*)&w1t[k*H + wid*8];
            *(float4*)&wv[4] = *(const float4*)&w1t[k*H + wid*8 + 4];
            #pragma unroll
            for (int oo=0;oo<8;oo++){ a1[oo]=fmaf(wv[oo],z.x,a1[oo]); jd1[oo]=fmaf(wv[oo],z.y,jd1[oo]); }
        }
        #pragma unroll
        for (int oo=0;oo<8;oo++) ws[OFF_A1 + (wid*8+oo)*B_TOT + e] = a1[oo];
        __syncthreads();            // all zj(L0) reads complete
        #pragma unroll
        for (int oo=0;oo<8;oo++){
            float s1=sigmoid_f(a1[oo]);
            zj[(wid*8+oo)*64+lane] = make_float2(softplus_f(a1[oo]), s1*jd1[oo]);
        }
        __syncthreads();

        // stage C: L2, m-slice 4 per wave (wid<7)
        if (wid<7){
            float x[4], xd[4];
            #pragma unroll
            for (int mm=0;mm<4;mm++){ x[mm]=bM2[wid*4+mm]; xd[mm]=0.f; }
            #pragma unroll 4
            for (int k=0;k<H;k++){
                float2 z = zj[k*64+lane];
                float wv[4];
                *(float4*)&wv[0] = *(const float4*)&w2t[k*MD + wid*4];
                #pragma unroll
                for (int mm=0;mm<4;mm++){ x[mm]=fmaf(wv[mm],z.x,x[mm]); xd[mm]=fmaf(wv[mm],z.y,xd[mm]); }
            }
            #pragma unroll
            for (int mm=0;mm<4;mm++){
                ws[OFF_X +(wid*4+mm)*B_TOT+e]=x[mm];
                ws[OFF_XD+(wid*4+mm)*B_TOT+e]=xd[mm];
            }
        }
    } else {
        // ---------------- V-net path ----------------
        float* zv0s=(float*)smem;             // [k][lane] softplus, 16 KB
        float* s0s =(float*)(smem+16384);     // [k][lane] sigmoid,  16 KB
        float* r1s =(float*)(smem+32768);     // [o][lane], 16 KB
        float* wv1t=(float*)(smem+49152);     // [k][o] transposed WV1, 16 KB
        float* red =(float*)(smem+32768);     // alias r1s after consumption
        const int e = ((int)blockIdx.x-256)*64 + lane;

        float qv[NQ];
        #pragma unroll
        for (int d=0;d<NQ;d++) qv[d]=q[e*NQ+d];

        for (int t=tid; t<H*H; t+=512) wv1t[(t&63)*H + (t>>6)] = WV1[t];

        // stage A: L0 for o-slice
        #pragma unroll
        for (int oo=0;oo<8;oo++){
            const int o=wid*8+oo;
            float a=bV0[o];
            #pragma unroll
            for (int d=0;d<NQ;d++) a=fmaf(WV0[o*NQ+d],qv[d],a);
            zv0s[o*64+lane]=softplus_f(a);
            s0s [o*64+lane]=sigmoid_f(a);
        }
        __syncthreads();

        // stage B: L1 forward for o-slice, k-outer
        float av1[8];
        #pragma unroll
        for (int oo=0;oo<8;oo++) av1[oo]=bV1[wid*8+oo];
        #pragma unroll 4
        for (int k=0;k<H;k++){
            float zk = zv0s[k*64+lane];
            float wv[8];
            *(float4*)&wv[0] = *(const float4*)&wv1t[k*H + wid*8];
            *(float4*)&wv[4] = *(const float4*)&wv1t[k*H + wid*8 + 4];
            #pragma unroll
            for (int oo=0;oo<8;oo++) av1[oo]=fmaf(wv[oo],zk,av1[oo]);
        }
        #pragma unroll
        for (int oo=0;oo<8;oo++){
            const int o=wid*8+oo;
            r1s[o*64+lane] = WV2[o]*sigmoid_f(av1[oo]);
        }
        // no sync needed: stage C reads only this wave's own r1 slice

        // stage C: partial racc over own o-slice (linear in r1 -> partials sum)
        float racc[64];
        #pragma unroll
        for (int k=0;k<H;k++) racc[k]=0.f;
        #pragma unroll
        for (int oo=0;oo<8;oo++){
            const int o=wid*8+oo;
            float r1o = r1s[o*64+lane];
            #pragma unroll
            for (int k=0;k<H;k++) racc[k]=fmaf(WV1[o*H+k],r1o,racc[k]);
        }
        float gp[NQ];
        #pragma unroll
        for (int d=0;d<NQ;d++) gp[d]=0.f;
        #pragma unroll
        for (int k=0;k<H;k++){
            float r0f = s0s[k*64+lane]*racc[k];
            #pragma unroll
            for (int d=0;d<NQ;d++) gp[d]=fmaf(WV0[k*NQ+d],r0f,gp[d]);
        }
        __syncthreads();            // everyone done with r1s before aliasing as red
        #pragma unroll
        for (int d=0;d<NQ;d++) red[(wid*NQ+d)*64+lane]=gp[d];
        __syncthreads();
        if (wid==0){
            #pragma unroll
            for (int w2=1;w2<8;w2++){
                #pragma unroll
                for (int d=0;d<NQ;d++) gp[d]+=red[(w2*NQ+d)*64+lane];
            }
            #pragma unroll
            for (int d=0;d<NQ;d++) ws[OFF_G + d*B_TOT + e]=gp[d];
        }
    }
}

// ======== KB: 7x7 eigen + Loewner -> sv, rp, Minv (unchanged from R8) ========
__global__ __launch_bounds__(64) void kb_eigen(
    const float* __restrict__ dq, const float* __restrict__ tau,
    float* __restrict__ ws)
{
    const int e = blockIdx.x*64 + threadIdx.x;

    float x[MD], xd[MD];
    #pragma unroll
    for (int m=0;m<MD;m++){ x[m]=ws[OFF_X+m*B_TOT+e]; xd[m]=ws[OFF_XD+m*B_TOT+e]; }

    float Ad[NQ], Ao[21], V[49];
    #pragma unroll
    for (int i=0;i<NQ;i++) Ad[i]=x[i];
    #pragma unroll
    for (int t=0;t<21;t++) Ao[t]=x[NQ+t];
    #pragma unroll
    for (int t=0;t<49;t++) V[t]=0.0f;
    #pragma unroll
    for (int i=0;i<NQ;i++) V[i*7+i]=1.0f;

    #pragma unroll 1
    for (int sweep=0; sweep<6; sweep++){
        #pragma unroll
        for (int p=0;p<6;p++){
            #pragma unroll
            for (int qq=p+1;qq<7;qq++){
                float app=Ad[p], aqq=Ad[qq], apq=Ao[OIDX(qq,p)];
                bool rot = fabsf(apq) > 1e-20f;
                float apq_s = rot ? apq : 1.0f;
                float theta = (aqq-app) * fast_rcp(2.0f*apq_s);
                float t = fast_rcp(fabsf(theta)+sqrtf(fmaf(theta,theta,1.0f)));
                t = (theta<0.0f)? -t : t;
                t = rot ? t : 0.0f;
                float c = rsqrtf(fmaf(t,t,1.0f));
                float s = t*c;
                #pragma unroll
                for (int j=0;j<7;j++){
                    if (j==p || j==qq) continue;
                    float ajp = (j<p)?  Ao[OIDX(p,j)]  : Ao[OIDX(j,p)];
                    float ajq = (j<qq)? Ao[OIDX(qq,j)] : Ao[OIDX(j,qq)];
                    float np_ = fmaf(c,ajp,-s*ajq);
                    float nq_ = fmaf(s,ajp, c*ajq);
                    if (j<p)  Ao[OIDX(p,j)]  = np_; else Ao[OIDX(j,p)]  = np_;
                    if (j<qq) Ao[OIDX(qq,j)] = nq_; else Ao[OIDX(j,qq)] = nq_;
                }
                Ad[p]  = fmaf(-t,apq,app);
                Ad[qq] = fmaf( t,apq,aqq);
                Ao[OIDX(qq,p)] = 0.0f;
                #pragma unroll
                for (int j=0;j<7;j++){
                    float vp=V[j*7+p], vq=V[j*7+qq];
                    V[j*7+p]  = fmaf(c,vp,-s*vq);
                    V[j*7+qq] = fmaf(s,vp, c*vq);
                }
            }
        }
    }

    float ee[7], iee[7];
    #pragma unroll
    for (int i=0;i<7;i++){ ee[i]=__expf(Ad[i]); iee[i]=fast_rcp(ee[i]); }

    float Ro[21];
    #pragma unroll
    for (int p=0;p<6;p++){
        #pragma unroll
        for (int qj=p+1;qj<7;qj++){
            float d = Ad[p]-Ad[qj];
            bool big = fabsf(d) > 1e-3f;
            float den = big ? d : 1.0f;
            float exact = (ee[p]-ee[qj])*fast_rcp(den);
            float ser = sqrtf(ee[p]*ee[qj]) * fmaf(d*d,(1.0f/24.0f),1.0f);
            Ro[OIDX(qj,p)] = big ? exact : ser;
        }
    }

    float dqv[7], tv[7];
    #pragma unroll
    for (int d=0;d<7;d++){ dqv[d]=dq[e*NQ+d]; tv[d]=tau[e*NQ+d]; }

    float w[7];
    #pragma unroll
    for (int a=0;a<7;a++){
        float acc=0.0f;
        #pragma unroll
        for (int j=0;j<7;j++) acc=fmaf(V[j*7+a],dqv[j],acc);
        w[a]=acc;
    }

    {
        float Yd[7], Yo[21];
        #pragma unroll
        for (int a=0;a<7;a++) Yd[a]=ee[a]*w[a]*w[a];
        #pragma unroll
        for (int p=0;p<6;p++){
            #pragma unroll
            for (int qj=p+1;qj<7;qj++) Yo[OIDX(qj,p)]=Ro[OIDX(qj,p)]*w[p]*w[qj];
        }
        float P[49];
        #pragma unroll
        for (int i=0;i<7;i++){
            #pragma unroll
            for (int a=0;a<7;a++){
                float acc=0.0f;
                #pragma unroll
                for (int c=0;c<7;c++){
                    float y=(c==a)? Yd[a] : ((c<a)? Yo[OIDX(a,c)] : Yo[OIDX(c,a)]);
                    acc=fmaf(V[i*7+c],y,acc);
                }
                P[i*7+a]=acc;
            }
        }
        #pragma unroll
        for (int i=0;i<7;i++){
            #pragma unroll
            for (int j=i;j<7;j++){
                float acc=0.0f;
                #pragma unroll
                for (int a=0;a<7;a++) acc=fmaf(P[i*7+a],V[j*7+a],acc);
                if (i==j) ws[OFF_SV + i*B_TOT + e]=acc;
                else      ws[OFF_SV + (NQ+OIDX(j,i))*B_TOT + e]=2.0f*acc;
            }
        }
    }

    {
        float P2[49];
        #pragma unroll
        for (int i=0;i<7;i++){
            #pragma unroll
            for (int a=0;a<7;a++){
                float acc=0.0f;
                #pragma unroll
                for (int j=0;j<7;j++){
                    float u=(i==j)? xd[i] : ((j<i)? xd[NQ+OIDX(i,j)] : xd[NQ+OIDX(j,i)]);
                    acc=fmaf(u,V[j*7+a],acc);
                }
                P2[i*7+a]=acc;
            }
        }
        float Td[7], To[21];
        #pragma unroll
        for (int a=0;a<7;a++){
            float acc=0.0f;
            #pragma unroll
            for (int i=0;i<7;i++) acc=fmaf(V[i*7+a],P2[i*7+a],acc);
            Td[a]=acc;
        }
        #pragma unroll
        for (int a=0;a<6;a++){
            #pragma unroll
            for (int bb=a+1;bb<7;bb++){
                float acc=0.0f;
                #pragma unroll
                for (int i=0;i<7;i++) acc=fmaf(V[i*7+a],P2[i*7+bb],acc);
                To[OIDX(bb,a)]=acc;
            }
        }
        float zw[7];
        #pragma unroll
        for (int a=0;a<7;a++){
            float acc=ee[a]*Td[a]*w[a];
            #pragma unroll
            for (int bb=0;bb<7;bb++){
                if (bb==a) continue;
                float z=(bb<a)? (Ro[OIDX(a,bb)]*To[OIDX(a,bb)]) : (Ro[OIDX(bb,a)]*To[OIDX(bb,a)]);
                acc=fmaf(z,w[bb],acc);
            }
            zw[a]=acc;
        }
        #pragma unroll
        for (int i=0;i<7;i++){
            float acc=0.0f;
            #pragma unroll
            for (int a=0;a<7;a++) acc=fmaf(V[i*7+a],zw[a],acc);
            ws[OFF_RP + i*B_TOT + e] = tv[i]-acc;
        }
    }

    #pragma unroll
    for (int i=0;i<7;i++){
        #pragma unroll
        for (int j=i;j<7;j++){
            float acc=0.0f;
            #pragma unroll
            for (int a=0;a<7;a++) acc=fmaf(V[i*7+a]*iee[a],V[j*7+a],acc);
            if (i==j) ws[OFF_MI + i*B_TOT + e]=acc;
            else      ws[OFF_MI + (NQ+OIDX(j,i))*B_TOT + e]=acc;
        }
    }
}

// ======== KD: M-net reverse (s), rhs, SPD solve -> out; 8 waves ========
__global__ __launch_bounds__(512) void kd_solve(
    const float* __restrict__ WM0, const float* __restrict__ WM1, const float* __restrict__ WM2,
    const float* __restrict__ ws,
    float* __restrict__ out)
{
    __shared__ __align__(16) float w2t[H*MD];   // [k][m]
    __shared__ float rr1fs[H*64];               // [k][lane]
    __shared__ float s0s[H*64];                 // [k][lane]
    const int tid=threadIdx.x, lane=tid&63, wid=tid>>6;
    const int e = blockIdx.x*64+lane;

    for (int t=tid;t<MD*H;t+=512) w2t[(t&63)*MD+(t>>6)] = WM2[t];

    float sv[MD];
    #pragma unroll
    for (int m=0;m<MD;m++) sv[m]=ws[OFF_SV+m*B_TOT+e];
    __syncthreads();

    // stage A: rr1f + sig(a0) for k-slice
    #pragma unroll
    for (int kk=0;kk<8;kk++){
        const int k=wid*8+kk;
        float wv[MD];
        #pragma unroll
        for (int c=0;c<7;c++) *(float4*)&wv[c*4] = *(const float4*)&w2t[k*MD + c*4];
        float acc=0.f;
        #pragma unroll
        for (int m=0;m<MD;m++) acc=fmaf(wv[m],sv[m],acc);
        float a1k=ws[OFF_A1+k*B_TOT+e];
        rr1fs[k*64+lane]=sigmoid_f(a1k)*acc;
        float a0k=ws[OFF_A0+k*B_TOT+e];
        s0s[k*64+lane]=sigmoid_f(a0k);
    }
    __syncthreads();

    // stage B: u partial over own i-slice (linear -> partials sum)
    float u[64];
    #pragma unroll
    for (int k=0;k<H;k++) u[k]=0.f;
    #pragma unroll
    for (int ii=0;ii<8;ii++){
        const int i=wid*8+ii;
        float r=rr1fs[i*64+lane];
        #pragma unroll
        for (int k=0;k<H;k++) u[k]=fmaf(WM1[i*H+k],r,u[k]);
    }

    // stage C: sp partial
    float sp[NQ];
    #pragma unroll
    for (int d=0;d<NQ;d++) sp[d]=0.f;
    #pragma unroll
    for (int k=0;k<H;k++){
        float t2=s0s[k*64+lane]*u[k];
        #pragma unroll
        for (int d=0;d<NQ;d++) sp[d]=fmaf(WM0[k*NQ+d],t2,sp[d]);
    }
    __syncthreads();            // all rr1fs reads done before aliasing as red
    float* red = rr1fs;
    #pragma unroll
    for (int d=0;d<NQ;d++) red[(wid*NQ+d)*64+lane]=sp[d];
    __syncthreads();

    if (wid==0){
        #pragma unroll
        for (int w2=1;w2<8;w2++){
            #pragma unroll
            for (int d=0;d<NQ;d++) sp[d]+=red[(w2*NQ+d)*64+lane];
        }
        float rhs[NQ], mi[MD];
        #pragma unroll
        for (int d=0;d<NQ;d++)
            rhs[d] = ws[OFF_RP + d*B_TOT + e] + 0.5f*sp[d] - ws[OFF_G + d*B_TOT + e];
        #pragma unroll
        for (int t=0;t<MD;t++) mi[t]=ws[OFF_MI + t*B_TOT + e];
        #pragma unroll
        for (int i=0;i<NQ;i++){
            float acc=0.0f;
            #pragma unroll
            for (int j=0;j<NQ;j++){
                int idx=(j==i)? i : (NQ + ((j>i)? OIDX(j,i) : OIDX(i,j)));
                acc=fmaf(mi[idx],rhs[j],acc);
            }
            out[e*NQ+i]=acc;
        }
    }
}

extern "C" void kernel_launch(void* const* d_in, const int* in_sizes, int n_in,
                              void* d_out, int out_size, void* d_ws, size_t ws_size,
                              hipStream_t stream) {
    const float* q   = (const float*)d_in[0];
    const float* dq  = (const float*)d_in[1];
    const float* tau = (const float*)d_in[2];
    const float* WM0 = (const float*)d_in[3];
    const float* bM0 = (const float*)d_in[4];
    const float* WM1 = (const float*)d_in[5];
    const float* bM1 = (const float*)d_in[6];
    const float* WM2 = (const float*)d_in[7];
    const float* bM2 = (const float*)d_in[8];
    const float* WV0 = (const float*)d_in[9];
    const float* bV0 = (const float*)d_in[10];
    const float* WV1 = (const float*)d_in[11];
    const float* bV1 = (const float*)d_in[12];
    const float* WV2 = (const float*)d_in[13];
    float* ws  = (float*)d_ws;
    float* out = (float*)d_out;

    hipLaunchKernelGGL(k_fwd,    dim3(512), dim3(512), 0, stream,
                       q, dq, WM0, bM0, WM1, bM1, WM2, bM2, WV0, bV0, WV1, bV1, WV2, ws);
    hipLaunchKernelGGL(kb_eigen, dim3(B_TOT/64), dim3(64), 0, stream, dq, tau, ws);
    hipLaunchKernelGGL(kd_solve, dim3(B_TOT/64), dim3(512), 0, stream, WM0, WM1, WM2, ws, out);
}